// Round 1
// baseline (571.502 us; speedup 1.0000x reference)
//
#include <hip/hip_runtime.h>

#define BATCH 4
#define NDIM 2048
#define EDIM 128
#define KDIM 3072
#define MDIM 8192   // BATCH*NDIM
#define HALF 15

// ---------------- K1: fp32 tiled GEMM with split-K ----------------
// y_part[in][kc][m][e] = sum_{k in chunk} x[m,k] * w[e,k]
#define BM 64
#define BK 32
#define LDA_S 72    // 64 m + 8 pad -> conflict-free transposed stores
#define LDW_S 136   // 128 e + 8 pad

__global__ __launch_bounds__(256, 2)
void k_gemm(const float* __restrict__ x0, const float* __restrict__ x1,
            const float* __restrict__ w, float* __restrict__ part, int splitK) {
  const int tid = threadIdx.x;
  const int m0 = blockIdx.x * BM;
  const int kc = blockIdx.y;
  const int inp = blockIdx.z;
  const float* __restrict__ x = inp ? x1 : x0;
  const int kpc = KDIM / splitK;
  const int kbeg = kc * kpc;
  const int kend = kbeg + kpc;

  __shared__ float sA[BK][LDA_S];   // [k][m]
  __shared__ float sW[BK][LDW_S];   // [k][e]

  const int lr = tid >> 3;          // 0..31 (row within tile for loads)
  const int lk = (tid & 7) << 2;    // 0,4,...,28 (k within tile)
  const int mg = tid >> 4;          // 0..15 compute m-group (4 m each)
  const int eg = tid & 15;          // 0..15 compute e-group (8 e each)

  float acc[4][8];
#pragma unroll
  for (int a = 0; a < 4; ++a)
#pragma unroll
    for (int q = 0; q < 8; ++q) acc[a][q] = 0.f;

  float4 ra0, ra1, rw0, rw1, rw2, rw3;
  {
    const float* xb = x + (size_t)(m0 + lr) * KDIM + kbeg + lk;
    ra0 = *(const float4*)xb;
    ra1 = *(const float4*)(xb + (size_t)32 * KDIM);
    const float* wb = w + (size_t)lr * KDIM + kbeg + lk;
    rw0 = *(const float4*)wb;
    rw1 = *(const float4*)(wb + (size_t)32 * KDIM);
    rw2 = *(const float4*)(wb + (size_t)64 * KDIM);
    rw3 = *(const float4*)(wb + (size_t)96 * KDIM);
  }

  for (int kt = kbeg; kt < kend; kt += BK) {
    __syncthreads();
#pragma unroll
    for (int j = 0; j < 4; ++j) {
      sA[lk + j][lr]      = ((const float*)&ra0)[j];
      sA[lk + j][lr + 32] = ((const float*)&ra1)[j];
      sW[lk + j][lr]      = ((const float*)&rw0)[j];
      sW[lk + j][lr + 32] = ((const float*)&rw1)[j];
      sW[lk + j][lr + 64] = ((const float*)&rw2)[j];
      sW[lk + j][lr + 96] = ((const float*)&rw3)[j];
    }
    __syncthreads();
    if (kt + BK < kend) {   // prefetch next tile under compute (T14 split)
      const float* xb = x + (size_t)(m0 + lr) * KDIM + (kt + BK) + lk;
      ra0 = *(const float4*)xb;
      ra1 = *(const float4*)(xb + (size_t)32 * KDIM);
      const float* wb = w + (size_t)lr * KDIM + (kt + BK) + lk;
      rw0 = *(const float4*)wb;
      rw1 = *(const float4*)(wb + (size_t)32 * KDIM);
      rw2 = *(const float4*)(wb + (size_t)64 * KDIM);
      rw3 = *(const float4*)(wb + (size_t)96 * KDIM);
    }
#pragma unroll
    for (int k = 0; k < BK; ++k) {
      float4 a4 = *(const float4*)&sA[k][mg << 2];
      float4 b0 = *(const float4*)&sW[k][eg << 3];
      float4 b1 = *(const float4*)&sW[k][(eg << 3) + 4];
      const float av[4] = {a4.x, a4.y, a4.z, a4.w};
      const float bv[8] = {b0.x, b0.y, b0.z, b0.w, b1.x, b1.y, b1.z, b1.w};
#pragma unroll
      for (int mi = 0; mi < 4; ++mi)
#pragma unroll
        for (int ei = 0; ei < 8; ++ei)
          acc[mi][ei] = fmaf(av[mi], bv[ei], acc[mi][ei]);
    }
  }

  float* po = part + ((size_t)(inp * splitK + kc) * MDIM + (m0 + (mg << 2))) * EDIM + (eg << 3);
#pragma unroll
  for (int mi = 0; mi < 4; ++mi) {
    float4 o0 = {acc[mi][0], acc[mi][1], acc[mi][2], acc[mi][3]};
    float4 o1 = {acc[mi][4], acc[mi][5], acc[mi][6], acc[mi][7]};
    *(float4*)(po + (size_t)mi * EDIM) = o0;
    *(float4*)(po + (size_t)mi * EDIM + 4) = o1;
  }
}

// ---------------- K2: reduce split-K, add bias, per-block BN partial sums ----------------
__global__ __launch_bounds__(256)
void k_reduce(const float* __restrict__ part, const float* __restrict__ bvec,
              float* __restrict__ y, float* __restrict__ spart, int splitK) {
  const int tid = threadIdx.x;
  const int in = blockIdx.z;
  const int rb = blockIdx.x;        // 128 row-blocks of 64 rows
  const int e = tid & 127;
  const int rh = tid >> 7;
  const float bb = bvec[e];
  float s = 0.f, s2 = 0.f;
  for (int rr = 0; rr < 32; ++rr) {
    const int r = rb * 64 + rh * 32 + rr;
    float v = 0.f;
    for (int kc = 0; kc < splitK; ++kc)
      v += part[((size_t)(in * splitK + kc) * MDIM + r) * EDIM + e];
    v += bb;
    y[((size_t)in * MDIM + r) * EDIM + e] = v;
    s += v; s2 += v * v;
  }
  __shared__ float l1[256], l2[256];
  l1[tid] = s; l2[tid] = s2;
  __syncthreads();
  if (rh == 0) {   // deterministic partials (no atomics -> replay-stable)
    s = l1[e] + l1[e + 128];
    s2 = l2[e] + l2[e + 128];
    spart[((size_t)(in * 128 + rb) * 2 + 0) * 128 + e] = s;
    spart[((size_t)(in * 128 + rb) * 2 + 1) * 128 + e] = s2;
  }
}

// ---------------- K3: finalize BN -> folded scale/shift ----------------
__global__ void k_finalize(const float* __restrict__ spart, const float* __restrict__ gamma,
                           const float* __restrict__ beta, float* __restrict__ scsh) {
  const int in = blockIdx.x;   // 0..1
  const int e = threadIdx.x;   // 0..127
  float s = 0.f, s2 = 0.f;
  for (int rb = 0; rb < 128; ++rb) {
    s  += spart[((size_t)(in * 128 + rb) * 2 + 0) * 128 + e];
    s2 += spart[((size_t)(in * 128 + rb) * 2 + 1) * 128 + e];
  }
  const float mu = s * (1.f / MDIM);
  const float var = s2 * (1.f / MDIM) - mu * mu;   // biased, matches reference
  const float rs = rsqrtf(var + 1e-5f);
  const float sc = gamma[e] * rs;
  const float sh = beta[e] - mu * sc;
  scsh[in * 128 + e] = sc;
  scsh[256 + in * 128 + e] = sh;
}

// ---------------- K4: apply BN + LeakyReLU(0.1) in place ----------------
__global__ __launch_bounds__(256)
void k_bnapply(float* __restrict__ y, const float* __restrict__ scsh) {
  int q = blockIdx.x * 256 + threadIdx.x;   // grid 1024 -> 262144 threads
  float4* yv = (float4*)y;
#pragma unroll
  for (int it = 0; it < 2; ++it, q += 262144) {
    float4 v = yv[q];
    const int in = q >> 18;            // 262144 float4 per input
    const int e0 = (q & 31) << 2;      // 32 float4 per row of 128
    const float* sc = scsh + in * 128 + e0;
    const float* sh = scsh + 256 + in * 128 + e0;
    float t;
    t = fmaf(sc[0], v.x, sh[0]); v.x = t >= 0.f ? t : 0.1f * t;
    t = fmaf(sc[1], v.y, sh[1]); v.y = t >= 0.f ? t : 0.1f * t;
    t = fmaf(sc[2], v.z, sh[2]); v.z = t >= 0.f ? t : 0.1f * t;
    t = fmaf(sc[3], v.w, sh[3]); v.w = t >= 0.f ? t : 0.1f * t;
    yv[q] = v;
  }
}

// ---------------- K5: banded sim + softmax; write full attn + compact band ----------------
__global__ __launch_bounds__(256)
void k_sim(const float* __restrict__ y, float* __restrict__ attn, float* __restrict__ aw) {
  const int tid = threadIdx.x;
  const int row = blockIdx.x * 4 + (tid >> 6);   // b*N+i, one wave per row
  const int lane = tid & 63;
  const int b = row >> 11;
  const int i = row & 2047;
  const int jlo = max(0, i - HALF);
  const int jhi = min(NDIM - 1, i + HALF);
  const int j = jlo + lane;
  const bool valid = (lane < 31) && (j <= jhi);
  const int jc = valid ? j : jlo;
  const float* __restrict__ xr = y + (size_t)row * EDIM;
  const float* __restrict__ tr = y + (size_t)MDIM * EDIM + ((size_t)(b << 11) + jc) * EDIM;
  float s = 0.f;
#pragma unroll
  for (int e = 0; e < EDIM; e += 4) {
    float4 u = *(const float4*)(xr + e);   // uniform -> broadcast
    float4 v = *(const float4*)(tr + e);   // per-lane row
    s = fmaf(u.x, v.x, s); s = fmaf(u.y, v.y, s);
    s = fmaf(u.z, v.z, s); s = fmaf(u.w, v.w, s);
  }
  float sm = valid ? s : -1e30f;
  float mx = sm;
#pragma unroll
  for (int o = 1; o < 64; o <<= 1) mx = fmaxf(mx, __shfl_xor(mx, o));
  const float p = valid ? __expf(sm - mx) : 0.f;
  float ss = p;
#pragma unroll
  for (int o = 1; o < 64; o <<= 1) ss += __shfl_xor(ss, o);
  const float a = p / ss;
  if (valid) attn[(size_t)row * NDIM + j] = a;
  if (lane < 32) aw[(size_t)row * 32 + lane] = valid ? a : 0.f;
}

// ---------------- K6: banded attn @ mem + blend with sig ----------------
#define TI 16
#define TJMAX 46
#define FC 256

__global__ __launch_bounds__(256, 2)
void k_memw(const float* __restrict__ sig, const float* __restrict__ mem,
            const float* __restrict__ aw, float* __restrict__ out) {
  const int tid = threadIdx.x;
  const int fc0 = blockIdx.x * FC;
  const int i0 = blockIdx.y * TI;
  const int b = blockIdx.z;
  const int jlo = max(0, i0 - HALF);
  const int jhi = min(NDIM - 1, i0 + TI - 1 + HALF);
  const int tj = jhi - jlo + 1;     // <= 46

  __shared__ float sV[TJMAX][FC];   // mem rows (f-chunk)
  __shared__ float sWt[TJMAX][TI];  // band weights, zeros outside band

  for (int idx = tid; idx < tj * TI; idx += 256) {
    const int jj = idx >> 4;
    const int ii = idx & 15;
    const int ii_g = i0 + ii;
    const int jg = jlo + jj;
    const int jli = max(0, ii_g - HALF);
    const int jhii = min(NDIM - 1, ii_g + HALF);
    float wv = 0.f;
    if (jg >= jli && jg <= jhii) wv = aw[(size_t)((b << 11) + ii_g) * 32 + (jg - jli)];
    sWt[jj][ii] = wv;
  }
  for (int idx = tid; idx < tj * (FC / 4); idx += 256) {
    const int jj = idx >> 6;
    const int f4 = idx & 63;
    *(float4*)&sV[jj][f4 << 2] =
        *(const float4*)(mem + (size_t)((b << 11) + jlo + jj) * KDIM + fc0 + (f4 << 2));
  }
  __syncthreads();

  const int ig = tid >> 6;          // wave id -> 4 i rows
  const int fg = tid & 63;          // lane -> 4 f
  const int ibase = i0 + (ig << 2);
  const int wlo = max(jlo, ibase - HALF) - jlo;
  const int whi = min(jhi, ibase + 3 + HALF) - jlo;

  float acc[4][4];
#pragma unroll
  for (int a = 0; a < 4; ++a)
#pragma unroll
    for (int c = 0; c < 4; ++c) acc[a][c] = 0.f;

  for (int jj = wlo; jj <= whi; ++jj) {   // <= 34 iters, wave-uniform bounds
    float4 wv = *(const float4*)&sWt[jj][ig << 2];   // wave-uniform -> broadcast
    float4 vv = *(const float4*)&sV[jj][fg << 2];    // consecutive -> conflict-free
    const float wa[4] = {wv.x, wv.y, wv.z, wv.w};
    const float va[4] = {vv.x, vv.y, vv.z, vv.w};
#pragma unroll
    for (int mi = 0; mi < 4; ++mi)
#pragma unroll
      for (int fi = 0; fi < 4; ++fi)
        acc[mi][fi] = fmaf(wa[mi], va[fi], acc[mi][fi]);
  }

  const size_t base = (size_t)((b << 11) + ibase) * KDIM + fc0 + (fg << 2);
#pragma unroll
  for (int mi = 0; mi < 4; ++mi) {
    float4 sv = *(const float4*)(sig + base + (size_t)mi * KDIM);
    float4 ov;
    ov.x = 0.5f * sv.x + 0.5f * acc[mi][0];
    ov.y = 0.5f * sv.y + 0.5f * acc[mi][1];
    ov.z = 0.5f * sv.z + 0.5f * acc[mi][2];
    ov.w = 0.5f * sv.w + 0.5f * acc[mi][3];
    *(float4*)(out + base + (size_t)mi * KDIM) = ov;
  }
}

extern "C" void kernel_launch(void* const* d_in, const int* in_sizes, int n_in,
                              void* d_out, int out_size, void* d_ws, size_t ws_size,
                              hipStream_t stream) {
  const float* sig   = (const float*)d_in[0];
  const float* mem   = (const float*)d_in[1];
  const float* w     = (const float*)d_in[2];
  const float* bv    = (const float*)d_in[3];
  const float* gamma = (const float*)d_in[4];
  const float* beta  = (const float*)d_in[5];

  float* out_mem  = (float*)d_out;
  float* out_attn = out_mem + (size_t)BATCH * NDIM * KDIM;   // 25,165,824

  float* wsf = (float*)d_ws;
  const size_t ME = (size_t)MDIM * EDIM;                      // 1,048,576
  const size_t fixed = 2 * ME + 65536 + 512 + 262144;
  int splitK = 4;
  while (splitK > 1 && ((size_t)2 * splitK * ME + fixed) * 4 > ws_size) splitK >>= 1;

  float* part  = wsf;
  float* y     = part + (size_t)2 * splitK * ME;
  float* spart = y + 2 * ME;
  float* scsh  = spart + 65536;
  float* aw    = scsh + 512;

  // zero the full attn output (band values overwritten by k_sim)
  hipMemsetAsync(out_attn, 0, (size_t)BATCH * NDIM * NDIM * sizeof(float), stream);

  dim3 g1(MDIM / BM, splitK, 2);
  hipLaunchKernelGGL(k_gemm, g1, dim3(256), 0, stream, sig, mem, w, part, splitK);

  dim3 g2(MDIM / 64, 1, 2);
  hipLaunchKernelGGL(k_reduce, g2, dim3(256), 0, stream, part, bv, y, spart, splitK);

  hipLaunchKernelGGL(k_finalize, dim3(2), dim3(128), 0, stream, spart, gamma, beta, scsh);

  hipLaunchKernelGGL(k_bnapply, dim3(1024), dim3(256), 0, stream, y, scsh);

  hipLaunchKernelGGL(k_sim, dim3(MDIM / 4), dim3(256), 0, stream, y, out_attn, aw);

  dim3 g6(KDIM / FC, NDIM / TI, BATCH);
  hipLaunchKernelGGL(k_memw, g6, dim3(256), 0, stream, sig, mem, aw, out_mem);
}

// Round 3
// 474.960 us; speedup vs baseline: 1.2033x; 1.2033x over previous
//
#include <hip/hip_runtime.h>

#define BATCH 4
#define NDIM 2048
#define EDIM 128
#define KDIM 3072
#define MDIM 8192   // BATCH*NDIM
#define HALF 15

typedef __attribute__((ext_vector_type(8))) short short8v;
typedef __attribute__((ext_vector_type(4))) float f32x4;

__device__ inline ushort bf16h(float x) {   // RNE fp32->bf16
  union { float f; unsigned u; } v; v.f = x;
  unsigned r = v.u + 0x7fff + ((v.u >> 16) & 1);
  return (ushort)(r >> 16);
}
__device__ inline float bf2f(ushort h) {
  union { unsigned u; float f; } v; v.u = ((unsigned)h) << 16;
  return v.f;
}

// ---------------- K1: MFMA bf16 hi/lo-split GEMM (3-term), split-K ----------------
// part[in][kc][m][e] = sum_k x[m,k]*w[e,k]; x,w fp32 -> hi/lo bf16 in LDS staging.
#define BMT 128   // m per block
#define BK 32     // k per step (one MFMA K)

__global__ __launch_bounds__(256, 2)
void k_gemm(const float* __restrict__ x0, const float* __restrict__ x1,
            const float* __restrict__ w, float* __restrict__ part, int splitK) {
  const int tid = threadIdx.x;
  const int m0 = blockIdx.x * BMT;
  const int kc = blockIdx.y;
  const int inp = blockIdx.z;
  const float* __restrict__ x = inp ? x1 : x0;
  const int kpc = KDIM / splitK;
  const int kbeg = kc * kpc;
  const int nsteps = kpc / BK;

  __shared__ ushort sAh[BMT][BK];   // 8KB each
  __shared__ ushort sAl[BMT][BK];
  __shared__ ushort sBh[EDIM][BK];
  __shared__ ushort sBl[EDIM][BK];

  // staging map: thread t -> rows (t>>3)+32i, k-chunk (t&7)*4  (8 lanes/row, coalesced)
  const int mrow = tid >> 3;
  const int c4 = (tid & 7) << 2;

  // compute map: 4 waves in 2x2 grid, each wave 64m x 64e = 4x4 fragments
  const int lane = tid & 63;
  const int wid = tid >> 6;
  const int wr = wid >> 1;
  const int wc = wid & 1;
  const int fr = lane & 15;
  const int kg = (lane >> 4) << 3;   // 0,8,16,24

  f32x4 acc[4][4];
#pragma unroll
  for (int a = 0; a < 4; ++a)
#pragma unroll
    for (int b = 0; b < 4; ++b) acc[a][b] = (f32x4){0.f, 0.f, 0.f, 0.f};

  float4 rA[4], rB[4];
  {
    const float* xb = x + (size_t)(m0 + mrow) * KDIM + kbeg + c4;
    const float* wb = w + (size_t)mrow * KDIM + kbeg + c4;
#pragma unroll
    for (int i = 0; i < 4; ++i) {
      rA[i] = *(const float4*)(xb + (size_t)(32 * i) * KDIM);
      rB[i] = *(const float4*)(wb + (size_t)(32 * i) * KDIM);
    }
  }

  for (int st = 0; st < nsteps; ++st) {
    __syncthreads();   // consumers of previous tile done
#pragma unroll
    for (int i = 0; i < 4; ++i) {
      const int m = mrow + 32 * i;
      const float fa[4] = {rA[i].x, rA[i].y, rA[i].z, rA[i].w};
      const float fb[4] = {rB[i].x, rB[i].y, rB[i].z, rB[i].w};
      ushort4 ah, al, bh, bl;
      ushort* pah = (ushort*)&ah; ushort* pal = (ushort*)&al;
      ushort* pbh = (ushort*)&bh; ushort* pbl = (ushort*)&bl;
#pragma unroll
      for (int j = 0; j < 4; ++j) {
        ushort h = bf16h(fa[j]); pah[j] = h; pal[j] = bf16h(fa[j] - bf2f(h));
        ushort g = bf16h(fb[j]); pbh[j] = g; pbl[j] = bf16h(fb[j] - bf2f(g));
      }
      *(ushort4*)&sAh[m][c4] = ah;
      *(ushort4*)&sAl[m][c4] = al;
      *(ushort4*)&sBh[m][c4] = bh;
      *(ushort4*)&sBl[m][c4] = bl;
    }
    __syncthreads();

    if (st + 1 < nsteps) {   // prefetch next fp32 tile under compute (T14)
      const int ko = kbeg + (st + 1) * BK + c4;
      const float* xb = x + (size_t)(m0 + mrow) * KDIM + ko;
      const float* wb = w + (size_t)mrow * KDIM + ko;
#pragma unroll
      for (int i = 0; i < 4; ++i) {
        rA[i] = *(const float4*)(xb + (size_t)(32 * i) * KDIM);
        rB[i] = *(const float4*)(wb + (size_t)(32 * i) * KDIM);
      }
    }

    short8v ah[4], al[4], bh[4], bl[4];
#pragma unroll
    for (int mi = 0; mi < 4; ++mi) {
      const int row = wr * 64 + mi * 16 + fr;
      ah[mi] = *(const short8v*)&sAh[row][kg];
      al[mi] = *(const short8v*)&sAl[row][kg];
    }
#pragma unroll
    for (int ei = 0; ei < 4; ++ei) {
      const int e = wc * 64 + ei * 16 + fr;
      bh[ei] = *(const short8v*)&sBh[e][kg];
      bl[ei] = *(const short8v*)&sBl[e][kg];
    }
#pragma unroll
    for (int mi = 0; mi < 4; ++mi)
#pragma unroll
      for (int ei = 0; ei < 4; ++ei) {
        acc[mi][ei] = __builtin_amdgcn_mfma_f32_16x16x32_bf16(ah[mi], bh[ei], acc[mi][ei], 0, 0, 0);
        acc[mi][ei] = __builtin_amdgcn_mfma_f32_16x16x32_bf16(ah[mi], bl[ei], acc[mi][ei], 0, 0, 0);
        acc[mi][ei] = __builtin_amdgcn_mfma_f32_16x16x32_bf16(al[mi], bh[ei], acc[mi][ei], 0, 0, 0);
      }
  }

  // C/D layout: e = lane&15, m = (lane>>4)*4 + reg   [m89-verified mapping]
  float* po = part + ((size_t)(inp * splitK + kc) * MDIM + m0) * EDIM;
#pragma unroll
  for (int mi = 0; mi < 4; ++mi) {
    const int mloc = wr * 64 + mi * 16 + ((lane >> 4) << 2);
#pragma unroll
    for (int ei = 0; ei < 4; ++ei) {
      const int e = wc * 64 + ei * 16 + fr;
#pragma unroll
      for (int r = 0; r < 4; ++r)
        po[(size_t)(mloc + r) * EDIM + e] = acc[mi][ei][r];
    }
  }
}

// ---------------- K2: reduce split-K, add bias, per-block BN partial sums ----------------
__global__ __launch_bounds__(256)
void k_reduce(const float* __restrict__ part, const float* __restrict__ bvec,
              float* __restrict__ y, float* __restrict__ spart, int splitK) {
  const int tid = threadIdx.x;
  const int in = blockIdx.z;
  const int rb = blockIdx.x;        // 128 row-blocks of 64 rows
  const int e = tid & 127;
  const int rh = tid >> 7;
  const float bb = bvec[e];
  float s = 0.f, s2 = 0.f;
  for (int rr = 0; rr < 32; ++rr) {
    const int r = rb * 64 + rh * 32 + rr;
    float v = 0.f;
    for (int kc = 0; kc < splitK; ++kc)
      v += part[((size_t)(in * splitK + kc) * MDIM + r) * EDIM + e];
    v += bb;
    y[((size_t)in * MDIM + r) * EDIM + e] = v;
    s += v; s2 += v * v;
  }
  __shared__ float l1[256], l2[256];
  l1[tid] = s; l2[tid] = s2;
  __syncthreads();
  if (rh == 0) {   // deterministic partials (no atomics -> replay-stable)
    s = l1[e] + l1[e + 128];
    s2 = l2[e] + l2[e + 128];
    spart[((size_t)(in * 128 + rb) * 2 + 0) * 128 + e] = s;
    spart[((size_t)(in * 128 + rb) * 2 + 1) * 128 + e] = s2;
  }
}

// ---------------- K3: finalize BN -> folded scale/shift ----------------
__global__ void k_finalize(const float* __restrict__ spart, const float* __restrict__ gamma,
                           const float* __restrict__ beta, float* __restrict__ scsh) {
  const int in = blockIdx.x;   // 0..1
  const int e = threadIdx.x;   // 0..127
  float s = 0.f, s2 = 0.f;
  for (int rb = 0; rb < 128; ++rb) {
    s  += spart[((size_t)(in * 128 + rb) * 2 + 0) * 128 + e];
    s2 += spart[((size_t)(in * 128 + rb) * 2 + 1) * 128 + e];
  }
  const float mu = s * (1.f / MDIM);
  const float var = s2 * (1.f / MDIM) - mu * mu;   // biased, matches reference
  const float rs = rsqrtf(var + 1e-5f);
  const float sc = gamma[e] * rs;
  const float sh = beta[e] - mu * sc;
  scsh[in * 128 + e] = sc;
  scsh[256 + in * 128 + e] = sh;
}

// ---------------- K4: apply BN + LeakyReLU(0.1) in place ----------------
__global__ __launch_bounds__(256)
void k_bnapply(float* __restrict__ y, const float* __restrict__ scsh) {
  int q = blockIdx.x * 256 + threadIdx.x;   // grid 1024 -> 262144 threads
  float4* yv = (float4*)y;
#pragma unroll
  for (int it = 0; it < 2; ++it, q += 262144) {
    float4 v = yv[q];
    const int in = q >> 18;            // 262144 float4 per input
    const int e0 = (q & 31) << 2;      // 32 float4 per row of 128
    const float* sc = scsh + in * 128 + e0;
    const float* sh = scsh + 256 + in * 128 + e0;
    float t;
    t = fmaf(sc[0], v.x, sh[0]); v.x = t >= 0.f ? t : 0.1f * t;
    t = fmaf(sc[1], v.y, sh[1]); v.y = t >= 0.f ? t : 0.1f * t;
    t = fmaf(sc[2], v.z, sh[2]); v.z = t >= 0.f ? t : 0.1f * t;
    t = fmaf(sc[3], v.w, sh[3]); v.w = t >= 0.f ? t : 0.1f * t;
    yv[q] = v;
  }
}

// ---------------- K5: banded sim + softmax; write full attn + compact band ----------------
__global__ __launch_bounds__(256)
void k_sim(const float* __restrict__ y, float* __restrict__ attn, float* __restrict__ aw) {
  const int tid = threadIdx.x;
  const int row = blockIdx.x * 4 + (tid >> 6);   // b*N+i, one wave per row
  const int lane = tid & 63;
  const int b = row >> 11;
  const int i = row & 2047;
  const int jlo = max(0, i - HALF);
  const int jhi = min(NDIM - 1, i + HALF);
  const int j = jlo + lane;
  const bool valid = (lane < 31) && (j <= jhi);
  const int jc = valid ? j : jlo;
  const float* __restrict__ xr = y + (size_t)row * EDIM;
  const float* __restrict__ tr = y + (size_t)MDIM * EDIM + ((size_t)(b << 11) + jc) * EDIM;
  float s = 0.f;
#pragma unroll
  for (int e = 0; e < EDIM; e += 4) {
    float4 u = *(const float4*)(xr + e);   // uniform -> broadcast
    float4 v = *(const float4*)(tr + e);   // per-lane row
    s = fmaf(u.x, v.x, s); s = fmaf(u.y, v.y, s);
    s = fmaf(u.z, v.z, s); s = fmaf(u.w, v.w, s);
  }
  float sm = valid ? s : -1e30f;
  float mx = sm;
#pragma unroll
  for (int o = 1; o < 64; o <<= 1) mx = fmaxf(mx, __shfl_xor(mx, o));
  const float p = valid ? __expf(sm - mx) : 0.f;
  float ss = p;
#pragma unroll
  for (int o = 1; o < 64; o <<= 1) ss += __shfl_xor(ss, o);
  const float a = p / ss;
  if (valid) attn[(size_t)row * NDIM + j] = a;
  if (lane < 32) aw[(size_t)row * 32 + lane] = valid ? a : 0.f;
}

// ---------------- K6: banded attn @ mem + blend with sig ----------------
#define TI 16
#define TJMAX 46
#define FC 256

__global__ __launch_bounds__(256, 2)
void k_memw(const float* __restrict__ sig, const float* __restrict__ mem,
            const float* __restrict__ aw, float* __restrict__ out) {
  const int tid = threadIdx.x;
  const int fc0 = blockIdx.x * FC;
  const int i0 = blockIdx.y * TI;
  const int b = blockIdx.z;
  const int jlo = max(0, i0 - HALF);
  const int jhi = min(NDIM - 1, i0 + TI - 1 + HALF);
  const int tj = jhi - jlo + 1;     // <= 46

  __shared__ float sV[TJMAX][FC];   // mem rows (f-chunk)
  __shared__ float sWt[TJMAX][TI];  // band weights, zeros outside band

  for (int idx = tid; idx < tj * TI; idx += 256) {
    const int jj = idx >> 4;
    const int ii = idx & 15;
    const int ii_g = i0 + ii;
    const int jg = jlo + jj;
    const int jli = max(0, ii_g - HALF);
    const int jhii = min(NDIM - 1, ii_g + HALF);
    float wv = 0.f;
    if (jg >= jli && jg <= jhii) wv = aw[(size_t)((b << 11) + ii_g) * 32 + (jg - jli)];
    sWt[jj][ii] = wv;
  }
  for (int idx = tid; idx < tj * (FC / 4); idx += 256) {
    const int jj = idx >> 6;
    const int f4 = idx & 63;
    *(float4*)&sV[jj][f4 << 2] =
        *(const float4*)(mem + (size_t)((b << 11) + jlo + jj) * KDIM + fc0 + (f4 << 2));
  }
  __syncthreads();

  const int ig = tid >> 6;          // wave id -> 4 i rows
  const int fg = tid & 63;          // lane -> 4 f
  const int ibase = i0 + (ig << 2);
  const int wlo = max(jlo, ibase - HALF) - jlo;
  const int whi = min(jhi, ibase + 3 + HALF) - jlo;

  float acc[4][4];
#pragma unroll
  for (int a = 0; a < 4; ++a)
#pragma unroll
    for (int c = 0; c < 4; ++c) acc[a][c] = 0.f;

  for (int jj = wlo; jj <= whi; ++jj) {   // <= 34 iters, wave-uniform bounds
    float4 wv = *(const float4*)&sWt[jj][ig << 2];   // wave-uniform -> broadcast
    float4 vv = *(const float4*)&sV[jj][fg << 2];    // consecutive -> conflict-free
    const float wa[4] = {wv.x, wv.y, wv.z, wv.w};
    const float va[4] = {vv.x, vv.y, vv.z, vv.w};
#pragma unroll
    for (int mi = 0; mi < 4; ++mi)
#pragma unroll
      for (int fi = 0; fi < 4; ++fi)
        acc[mi][fi] = fmaf(wa[mi], va[fi], acc[mi][fi]);
  }

  const size_t base = (size_t)((b << 11) + ibase) * KDIM + fc0 + (fg << 2);
#pragma unroll
  for (int mi = 0; mi < 4; ++mi) {
    float4 sv = *(const float4*)(sig + base + (size_t)mi * KDIM);
    float4 ov;
    ov.x = 0.5f * sv.x + 0.5f * acc[mi][0];
    ov.y = 0.5f * sv.y + 0.5f * acc[mi][1];
    ov.z = 0.5f * sv.z + 0.5f * acc[mi][2];
    ov.w = 0.5f * sv.w + 0.5f * acc[mi][3];
    *(float4*)(out + base + (size_t)mi * KDIM) = ov;
  }
}

extern "C" void kernel_launch(void* const* d_in, const int* in_sizes, int n_in,
                              void* d_out, int out_size, void* d_ws, size_t ws_size,
                              hipStream_t stream) {
  const float* sig   = (const float*)d_in[0];
  const float* mem   = (const float*)d_in[1];
  const float* w     = (const float*)d_in[2];
  const float* bv    = (const float*)d_in[3];
  const float* gamma = (const float*)d_in[4];
  const float* beta  = (const float*)d_in[5];

  float* out_mem  = (float*)d_out;
  float* out_attn = out_mem + (size_t)BATCH * NDIM * KDIM;   // 25,165,824

  float* wsf = (float*)d_ws;
  const size_t ME = (size_t)MDIM * EDIM;                      // 1,048,576
  const size_t fixed = 2 * ME + 65536 + 512 + 262144;
  int splitK = 4;
  while (splitK > 1 && ((size_t)2 * splitK * ME + fixed) * 4 > ws_size) splitK >>= 1;

  float* part  = wsf;
  float* y     = part + (size_t)2 * splitK * ME;
  float* spart = y + 2 * ME;
  float* scsh  = spart + 65536;
  float* aw    = scsh + 512;

  // zero the full attn output (band values overwritten by k_sim)
  hipMemsetAsync(out_attn, 0, (size_t)BATCH * NDIM * NDIM * sizeof(float), stream);

  dim3 g1(MDIM / BMT, splitK, 2);
  hipLaunchKernelGGL(k_gemm, g1, dim3(256), 0, stream, sig, mem, w, part, splitK);

  dim3 g2(MDIM / 64, 1, 2);
  hipLaunchKernelGGL(k_reduce, g2, dim3(256), 0, stream, part, bv, y, spart, splitK);

  hipLaunchKernelGGL(k_finalize, dim3(2), dim3(128), 0, stream, spart, gamma, beta, scsh);

  hipLaunchKernelGGL(k_bnapply, dim3(1024), dim3(256), 0, stream, y, scsh);

  hipLaunchKernelGGL(k_sim, dim3(MDIM / 4), dim3(256), 0, stream, y, out_attn, aw);

  dim3 g6(KDIM / FC, NDIM / TI, BATCH);
  hipLaunchKernelGGL(k_memw, g6, dim3(256), 0, stream, sig, mem, aw, out_mem);
}